// Round 13
// baseline (317.314 us; speedup 1.0000x reference)
//
#include <hip/hip_runtime.h>
#include <hip/hip_bf16.h>
#include <cmath>

// Problem constants
#define B_ 2
#define NQ_ 900
#define N_ 4096
#define LOG2E 1.4426950408889634f

typedef __attribute__((ext_vector_type(4))) float f32x4;
typedef __attribute__((ext_vector_type(8))) short s16x8;
typedef __attribute__((ext_vector_type(8))) _Float16 f16x8;

__device__ inline short f2bf(float x) {
    union { __hip_bfloat16 b; short s; } u;
    u.b = __float2bfloat16(x);
    return u.s;
}
__device__ inline short f2h(float x) {
    _Float16 h = (_Float16)x;
    return __builtin_bit_cast(short, h);
}

// DPP rotate within 16-lane row (VALU pipe; replaces ds_bpermute shuffles)
template <int CTRL>
__device__ inline float dppf(float x) {
    int xi = __builtin_bit_cast(int, x);
    int r = __builtin_amdgcn_update_dpp(xi, xi, CTRL, 0xF, 0xF, true);
    return __builtin_bit_cast(float, r);
}
__device__ inline float rowmax16(float v) {
    v = fmaxf(v, dppf<0x121>(v));
    v = fmaxf(v, dppf<0x122>(v));
    v = fmaxf(v, dppf<0x124>(v));
    v = fmaxf(v, dppf<0x128>(v));
    return v;
}
__device__ inline float rowsum16(float v) {
    v += dppf<0x121>(v);
    v += dppf<0x122>(v);
    v += dppf<0x124>(v);
    v += dppf<0x128>(v);
    return v;
}

// ---------------------------------------------------------------------------
// Stage 1 v3 (FUSED proj + rpe3 + Wp-prep + counter zeroing).
//  blocks 0..284  : proj, A-fragments in registers, Bb full-K 32 KB LDS
//  blocks 285..734: rpe3, 4 queries/block
//  blocks 735..750: Wp -> transposed f16 hi/lo pairs; tile 0 also zeros the
//                   58 fan-in counters used by attn's fused outproj epilogue.
// ---------------------------------------------------------------------------
__global__ __launch_bounds__(256) void stage1_kernel(
    const float* __restrict__ query, const float* __restrict__ kin,
    const float* __restrict__ vin,
    const float* __restrict__ Wq, const float* __restrict__ Wk,
    const float* __restrict__ Wv, const float* __restrict__ Wp,
    const float* __restrict__ bqv, const float* __restrict__ bkv,
    const float* __restrict__ bvv,
    unsigned short* __restrict__ qbf, unsigned short* __restrict__ kbf,
    unsigned short* __restrict__ vbf, float qscale,
    const float* __restrict__ ref2d,
    const float* __restrict__ W1x, const float* __restrict__ b1x,
    const float* __restrict__ W1y, const float* __restrict__ b1y,
    const float* __restrict__ W2x, const float* __restrict__ W2y,
    float* __restrict__ rpe_x, float* __restrict__ rpe_y,
    unsigned short* __restrict__ wph, unsigned short* __restrict__ wpl,
    unsigned int* __restrict__ cnt)
{
    __shared__ uint4 smem[2560];          // 40 KB union
    const int bx = blockIdx.x;
    const int tid = threadIdx.x;
    const int w = tid >> 6, l = tid & 63, quad = l >> 4, l15 = l & 15;

    if (bx < 285) {
        // ------------------------------ proj ------------------------------
        short* Bb = (short*)smem;                    // 32 KB (full K, one n-tile)
        const int mtx = bx < 29 ? 0 : (bx < 157 ? 1 : 2);
        const int tile = bx - (mtx == 0 ? 0 : mtx == 1 ? 29 : 157);
        const int m0 = tile * 64;
        const float* X = mtx == 0 ? query : mtx == 1 ? kin : vin;
        const float* W = mtx == 0 ? Wq : mtx == 1 ? Wk : Wv;
        const float* bias = mtx == 0 ? bqv : mtx == 1 ? bkv : bvv;
        unsigned short* Y = mtx == 0 ? qbf : mtx == 1 ? kbf : vbf;
        const int M = mtx == 0 ? 1800 : 8192;
        const float alpha = mtx == 0 ? qscale : 1.0f;
        const int rows_per_b = mtx == 0 ? 900 : 4096;
        const int ROWS = mtx == 0 ? 960 : 4096;
        const int wq = tid & 3, mm = tid >> 2;

        // A-fragments in registers: row = m0 + w*16 + l15, k = kc*32+quad*8+j
        s16x8 afr[8];
        {
            const int arow = m0 + w * 16 + l15;
            const bool avalid = arow < M;
            const float* xr = X + (size_t)arow * 256;
            #pragma unroll
            for (int kc = 0; kc < 8; ++kc) {
                float4 a0 = make_float4(0.f, 0.f, 0.f, 0.f), a1 = a0;
                if (avalid) {
                    a0 = *(const float4*)(xr + kc * 32 + quad * 8);
                    a1 = *(const float4*)(xr + kc * 32 + quad * 8 + 4);
                }
                unsigned pk0 = (unsigned)(unsigned short)f2bf(a0.x) | ((unsigned)(unsigned short)f2bf(a0.y) << 16);
                unsigned pk1 = (unsigned)(unsigned short)f2bf(a0.z) | ((unsigned)(unsigned short)f2bf(a0.w) << 16);
                unsigned pk2 = (unsigned)(unsigned short)f2bf(a1.x) | ((unsigned)(unsigned short)f2bf(a1.y) << 16);
                unsigned pk3 = (unsigned)(unsigned short)f2bf(a1.z) | ((unsigned)(unsigned short)f2bf(a1.w) << 16);
                uint4 pk = make_uint4(pk0, pk1, pk2, pk3);
                afr[kc] = __builtin_bit_cast(s16x8, pk);
            }
        }

        for (int nt0 = 0; nt0 < 4; ++nt0) {
            const int n0 = nt0 * 64;
            {
                const float* wcol = W + n0 + mm;
                #pragma unroll
                for (int it = 0; it < 8; ++it) {
                    int g2 = it * 4 + wq;
                    uint4 wk4;
                    wk4.x = (unsigned)(unsigned short)f2bf(wcol[(g2 * 8 + 0) * 256])
                          | ((unsigned)(unsigned short)f2bf(wcol[(g2 * 8 + 1) * 256]) << 16);
                    wk4.y = (unsigned)(unsigned short)f2bf(wcol[(g2 * 8 + 2) * 256])
                          | ((unsigned)(unsigned short)f2bf(wcol[(g2 * 8 + 3) * 256]) << 16);
                    wk4.z = (unsigned)(unsigned short)f2bf(wcol[(g2 * 8 + 4) * 256])
                          | ((unsigned)(unsigned short)f2bf(wcol[(g2 * 8 + 5) * 256]) << 16);
                    wk4.w = (unsigned)(unsigned short)f2bf(wcol[(g2 * 8 + 6) * 256])
                          | ((unsigned)(unsigned short)f2bf(wcol[(g2 * 8 + 7) * 256]) << 16);
                    *(uint4*)(Bb + (it * 256 + mm * 4 + wq) * 8) = wk4;
                }
            }
            __syncthreads();

            f32x4 acc[4] = {{0.f,0.f,0.f,0.f},{0.f,0.f,0.f,0.f},{0.f,0.f,0.f,0.f},{0.f,0.f,0.f,0.f}};
            #pragma unroll
            for (int kc = 0; kc < 8; ++kc) {
                #pragma unroll
                for (int nt = 0; nt < 4; ++nt) {
                    s16x8 bf = *(const s16x8*)(Bb + (kc * 256 + (nt * 16 + l15) * 4 + quad) * 8);
                    acc[nt] = __builtin_amdgcn_mfma_f32_16x16x32_bf16(afr[kc], bf, acc[nt], 0, 0, 0);
                }
            }

            #pragma unroll
            for (int nt = 0; nt < 4; ++nt) {
                int n = n0 + nt * 16 + l15;
                float bs = bias[n];
                int h = n >> 5, d = n & 31;
                #pragma unroll
                for (int r = 0; r < 4; ++r) {
                    int row = m0 + w * 16 + quad * 4 + r;
                    if (row < M) {
                        int b = row / rows_per_b;
                        int pos = row - b * rows_per_b;
                        Y[((size_t)(b * 8 + h) * ROWS + pos) * 32 + d] =
                            (unsigned short)f2bf((acc[nt][r] + bs) * alpha);
                    }
                }
            }
            __syncthreads();
        }
    } else if (bx < 735) {
        // ------------------------------ rpe3 ------------------------------
        short* sw2h = (short*)smem;                  // 16 KB
        short* sw2l = (short*)smem + 8192;           // 16 KB
        float4* sUV = (float4*)(smem + 2048);        // 8 KB, unpadded
        const int bq0 = (bx - 285) * 4;              // 4 queries per block

        for (int i = tid; i < 8192; i += 256) {
            int g = i >> 3, j = i & 7;
            int kcg = g >> 6, rr = g & 63, n = rr >> 2, q4 = rr & 3;
            int k = kcg * 32 + q4 * 8 + j;
            float val = ((n < 8) ? W2x[k * 8 + n] : W2y[k * 8 + (n - 8)]) * LOG2E;
            _Float16 hi = (_Float16)val;
            sw2h[i] = __builtin_bit_cast(short, hi);
            sw2l[i] = f2h(val - (float)hi);
        }

        // hoist W1 coefficients (k0 = tid, k1 = tid+256) + query-independent v
        const int k0 = tid, k1 = tid + 256;
        const float w1x0a = W1x[k0], w1x1a = W1x[512 + k0];
        const float w1y0a = W1y[k0], w1y1a = W1y[512 + k0];
        const float bxa = b1x[k0], bya = b1y[k0];
        const float vxa = -(w1x0a + w1x1a), vya = -(w1y0a + w1y1a);
        const float w1x0b = W1x[k1], w1x1b = W1x[512 + k1];
        const float w1y0b = W1y[k1], w1y1b = W1y[512 + k1];
        const float bxb = b1x[k1], byb = b1y[k1];
        const float vxb = -(w1x0b + w1x1b), vyb = -(w1y0b + w1y1b);

        const int wrow = w;
        const int row = wrow * 16 + l15;
        const float pc = (row + 0.5f) * 16.0f;

        for (int qi = 0; qi < 4; ++qi) {
            const int bq = bq0 + qi;
            {
                const float4 bb = *(const float4*)(ref2d + (size_t)bq * 4);
                float x1 = bb.x - bb.z * 0.5f, x2 = bb.x + bb.z * 0.5f;
                float y1 = bb.y - bb.w * 0.5f, y2 = bb.y + bb.w * 0.5f;
                sUV[k0] = make_float4(fmaf(w1x0a, x1, fmaf(w1x1a, x2, bxa)), vxa,
                                      fmaf(w1y0a, y1, fmaf(w1y1a, y2, bya)), vya);
                sUV[k1] = make_float4(fmaf(w1x0b, x1, fmaf(w1x1b, x2, bxb)), vxb,
                                      fmaf(w1y0b, y1, fmaf(w1y1b, y2, byb)), vyb);
            }
            __syncthreads();

            f32x4 accx = {0.f, 0.f, 0.f, 0.f}, accy = {0.f, 0.f, 0.f, 0.f};
            for (int kc = 0; kc < 16; ++kc) {
                f16x8 axh, axl, ayh, ayl;
                #pragma unroll
                for (int i = 0; i < 8; ++i) {
                    float4 u = sUV[kc * 32 + quad * 8 + i];
                    float hx = fmaxf(fmaf(u.y, pc, u.x), 0.f);
                    float hy = fmaxf(fmaf(u.w, pc, u.z), 0.f);
                    _Float16 xh = (_Float16)hx;
                    _Float16 yh = (_Float16)hy;
                    axh[i] = xh;
                    axl[i] = (_Float16)(hx - (float)xh);
                    ayh[i] = yh;
                    ayl[i] = (_Float16)(hy - (float)yh);
                }
                f16x8 bh = *(const f16x8*)(sw2h + (kc * 64 + l15 * 4 + quad) * 8);
                f16x8 bl = *(const f16x8*)(sw2l + (kc * 64 + l15 * 4 + quad) * 8);
                accx = __builtin_amdgcn_mfma_f32_16x16x32_f16(axh, bh, accx, 0, 0, 0);
                accx = __builtin_amdgcn_mfma_f32_16x16x32_f16(axh, bl, accx, 0, 0, 0);
                accx = __builtin_amdgcn_mfma_f32_16x16x32_f16(axl, bh, accx, 0, 0, 0);
                accy = __builtin_amdgcn_mfma_f32_16x16x32_f16(ayh, bh, accy, 0, 0, 0);
                accy = __builtin_amdgcn_mfma_f32_16x16x32_f16(ayh, bl, accy, 0, 0, 0);
                accy = __builtin_amdgcn_mfma_f32_16x16x32_f16(ayl, bh, accy, 0, 0, 0);
            }

            #pragma unroll
            for (int rr = 0; rr < 4; ++rr) {
                int row_out = wrow * 16 + quad * 4 + rr;
                if (l15 < 8) rpe_x[((size_t)l15 * 1800 + bq) * 64 + row_out] = accx[rr];
                else         rpe_y[((size_t)(l15 - 8) * 1800 + bq) * 64 + row_out] = accy[rr];
            }
            __syncthreads();   // before next query overwrites sUV
        }
    } else {
        // --------------------- Wp -> f16 hi/lo W^T ------------------------
        const int tile = bx - 735;                   // 0..15
        const int kt = tile >> 2, ntile = tile & 3;
        if (tile == 0 && tid < 58) cnt[tid] = 0;     // fan-in counters for attn
        unsigned short* th = (unsigned short*)smem;  // 64*72 ushort = 9.2 KB
        unsigned short* tl = th + 64 * 72;           // 9.2 KB
        #pragma unroll
        for (int p = 0; p < 4; ++p) {
            int kl = p * 16 + (tid >> 4);
            int nl = (tid & 15) * 4;
            float4 v = *(const float4*)(Wp + (size_t)(kt * 64 + kl) * 256 + ntile * 64 + nl);
            float vv[4] = {v.x, v.y, v.z, v.w};
            #pragma unroll
            for (int i = 0; i < 4; ++i) {
                _Float16 h = (_Float16)vv[i];
                th[(nl + i) * 72 + kl] = (unsigned short)__builtin_bit_cast(short, h);
                tl[(nl + i) * 72 + kl] = (unsigned short)f2h(vv[i] - (float)h);
            }
        }
        __syncthreads();
        #pragma unroll
        for (int p = 0; p < 2; ++p) {
            int nl = p * 32 + (tid >> 3);
            int k8 = (tid & 7) * 8;
            uint4 pk;
            unsigned short* ps = (unsigned short*)&pk;
            #pragma unroll
            for (int j = 0; j < 8; ++j) ps[j] = th[nl * 72 + k8 + j];
            *(uint4*)(wph + (size_t)(ntile * 64 + nl) * 256 + kt * 64 + k8) = pk;
            #pragma unroll
            for (int j = 0; j < 8; ++j) ps[j] = tl[nl * 72 + k8 + j];
            *(uint4*)(wpl + (size_t)(ntile * 64 + nl) * 256 + kt * 64 + k8) = pk;
        }
    }
}

// ---------------------------------------------------------------------------
// MFMA flash attention + FUSED outproj epilogue (fan-in atomics).
// Main loop is the round-1/8 verified config, untouched. After writing its
// xws slice, each block releases (threadfence) and bumps cnt[b*29+qb]; the
// 8th arriver (all heads done for this q-tile) runs the 32-row outproj tile
// inline (round-12 zero-LDS register outproj, 512-thread layout) -> kills
// the third kernel launch + its boundary.
// ---------------------------------------------------------------------------
__global__ __launch_bounds__(512, 4) void attn_mfma_kernel(
    const unsigned short* __restrict__ qb16, const unsigned short* __restrict__ kb16,
    const unsigned short* __restrict__ vb16,
    const float* __restrict__ rpe_x, const float* __restrict__ rpe_y,
    const unsigned char* __restrict__ mask, float* __restrict__ xout,
    const unsigned short* __restrict__ wph, const unsigned short* __restrict__ wpl,
    const float* __restrict__ bp, float* __restrict__ out,
    unsigned int* __restrict__ cnt)
{
    __shared__ short skf[4 * 2048];
    __shared__ short svt[4 * 2048];
    __shared__ short spb[8 * 544];
    __shared__ float ry[32 * 65];
    __shared__ unsigned long long smaskb[64];
    __shared__ float sm[8][16], sl[8][16], sLf[32];
    __shared__ unsigned int sArrive;

    const int tid = threadIdx.x;
    const int qb = blockIdx.x, h = blockIdx.y, b = blockIdx.z;
    const int q0 = qb * 32;
    const int w = tid >> 6, l = tid & 63;
    const int qsub = w >> 2, g = w & 3;
    const int quad = l >> 4, l15 = l & 15;

    const unsigned short* qg = qb16 + (size_t)(b * 8 + h) * 960 * 32;
    const unsigned short* kg = kb16 + (size_t)(b * 8 + h) * 4096 * 32;
    const unsigned short* vg = vb16 + (size_t)(b * 8 + h) * 4096 * 32;
    const float* rxh = rpe_x + ((size_t)h * 1800 + b * NQ_) * 64;
    const float* ryh = rpe_y + ((size_t)h * 1800 + b * NQ_) * 64;

    for (int i = tid; i < 2048; i += 512) {
        int qq = q0 + (i >> 6), pos = i & 63;
        float vy = 0.f;
        if (qq < NQ_)
            vy = ryh[(size_t)qq * 64 + pos];
        ry[(i >> 6) * 65 + pos] = vy;
    }
    #pragma unroll
    for (int j = 0; j < 8; ++j) {
        int c = w * 8 + j;
        unsigned long long bits = __ballot(mask[(size_t)b * N_ + c * 64 + l] != 0);
        if (l == 0) smaskb[c] = bits;
    }

    s16x8 qa = *(const s16x8*)(qg + (size_t)(q0 + qsub * 16 + l15) * 32 + quad * 8);

    f32x4 rx4[4];
    #pragma unroll
    for (int t = 0; t < 4; ++t)
        #pragma unroll
        for (int r = 0; r < 4; ++r) {
            int qq = q0 + qsub * 16 + quad * 4 + r;
            rx4[t][r] = (qq < NQ_) ? rxh[(size_t)qq * 64 + t * 16 + l15] : 0.f;
        }

    const int sg = tid >> 7, role = (tid >> 6) & 1, stl = tid & 63;
    int eoff[4];
    if (role == 0) {
        #pragma unroll
        for (int t = 0; t < 4; ++t)
            eoff[t] = (t * 16 + (stl & 15)) * 32 + (stl >> 4) * 8;
    } else {
        #pragma unroll
        for (int t = 0; t < 4; ++t)
            eoff[t] = stl * 32 + t * 8;
    }
    const unsigned short* src = role ? vg : kg;

    uint4 pf[4];
    {
        size_t cb = (size_t)(sg * 16) * 2048;
        #pragma unroll
        for (int t = 0; t < 4; ++t) pf[t] = *(const uint4*)(src + cb + eoff[t]);
    }

    float mrow[4] = {-INFINITY, -INFINITY, -INFINITY, -INFINITY};
    float lrow[4] = {0.f, 0.f, 0.f, 0.f};
    f32x4 acc0 = {0.f, 0.f, 0.f, 0.f}, acc1 = {0.f, 0.f, 0.f, 0.f};
    short* pw = spb + w * 544;

    for (int i = 0; i < 16; ++i) {
        __syncthreads();
        if (role == 0) {
            #pragma unroll
            for (int t = 0; t < 4; ++t)
                *(uint4*)(skf + sg * 2048 + (t * 64 + stl) * 8) = pf[t];
        } else {
            short* vtw = svt + sg * 2048;
            #pragma unroll
            for (int t = 0; t < 4; ++t) {
                const unsigned short* pv = (const unsigned short*)&pf[t];
                #pragma unroll
                for (int j = 0; j < 8; ++j) {
                    int d = t * 8 + j;
                    vtw[d * 64 + (((stl >> 3) ^ (d & 7)) << 3) + (stl & 7)] = (short)pv[j];
                }
            }
        }
        __syncthreads();

        {
            int inext = (i + 1 < 16) ? i + 1 : 15;
            size_t cb = (size_t)(sg * 16 + inext) * 2048;
            #pragma unroll
            for (int t = 0; t < 4; ++t) pf[t] = *(const uint4*)(src + cb + eoff[t]);
        }

        const int cgc = g * 16 + i;
        const short* kf = skf + g * 2048;

        f32x4 sc[4];
        #pragma unroll
        for (int t = 0; t < 4; ++t) {
            s16x8 kb = *(const s16x8*)(kf + (t * 64 + l) * 8);
            sc[t] = __builtin_amdgcn_mfma_f32_16x16x32_bf16(qa, kb, rx4[t], 0, 0, 0);
        }
        float ryv[4];
        #pragma unroll
        for (int r = 0; r < 4; ++r)
            ryv[r] = ry[(qsub * 16 + quad * 4 + r) * 65 + cgc];
        unsigned long long mb = smaskb[cgc];
        if (mb) {
            #pragma unroll
            for (int t = 0; t < 4; ++t) {
                float mk = ((mb >> (t * 16 + l15)) & 1ULL) ? -144.2695f : 0.f;
                #pragma unroll
                for (int r = 0; r < 4; ++r) sc[t][r] += mk;
            }
        }

        float cmr[4];
        #pragma unroll
        for (int r = 0; r < 4; ++r)
            cmr[r] = fmaxf(fmaxf(sc[0][r], sc[1][r]), fmaxf(sc[2][r], sc[3][r])) + ryv[r];

        int ok = (cmr[0] <= mrow[0] + 8.f) & (cmr[1] <= mrow[1] + 8.f)
               & (cmr[2] <= mrow[2] + 8.f) & (cmr[3] <= mrow[3] + 8.f);
        if (!__all(ok)) {
            #pragma unroll
            for (int r = 0; r < 4; ++r) {
                float cm = rowmax16(cmr[r]);
                float mnew = fmaxf(mrow[r], cm);
                float al = exp2f(mrow[r] - mnew);
                mrow[r] = mnew;
                lrow[r] *= al;
                acc0[r] *= al;
                acc1[r] *= al;
            }
        }

        float msub[4];
        #pragma unroll
        for (int r = 0; r < 4; ++r) msub[r] = mrow[r] - ryv[r];
        #pragma unroll
        for (int t = 0; t < 4; ++t)
            #pragma unroll
            for (int r = 0; r < 4; ++r)
                sc[t][r] = exp2f(sc[t][r] - msub[r]);
        #pragma unroll
        for (int r = 0; r < 4; ++r)
            lrow[r] += (sc[0][r] + sc[1][r]) + (sc[2][r] + sc[3][r]);

        const short* vt = svt + g * 2048;
        #pragma unroll
        for (int hh = 0; hh < 2; ++hh) {
            #pragma unroll
            for (int tt = 0; tt < 2; ++tt) {
                int t = hh * 2 + tt;
                int gphys = (tt * 2 + (l15 >> 3)) ^ quad;
                #pragma unroll
                for (int r = 0; r < 4; ++r)
                    pw[(gphys * 17 + quad * 4 + r) * 8 + (l15 & 7)] = f2bf(sc[t][r]);
            }
            int gph_r = quad ^ (l15 >> 2);
            s16x8 pa  = *(const s16x8*)(pw + (gph_r * 17 + l15) * 8);
            int ksw = ((hh * 4 + quad) ^ (l15 & 7)) * 8;
            s16x8 vb0 = *(const s16x8*)(vt + l15 * 64 + ksw);
            s16x8 vb1 = *(const s16x8*)(vt + (16 + l15) * 64 + ksw);
            acc0 = __builtin_amdgcn_mfma_f32_16x16x32_bf16(pa, vb0, acc0, 0, 0, 0);
            acc1 = __builtin_amdgcn_mfma_f32_16x16x32_bf16(pa, vb1, acc1, 0, 0, 0);
        }
    }

    #pragma unroll
    for (int r = 0; r < 4; ++r) lrow[r] = rowsum16(lrow[r]);

    __syncthreads();
    if (l15 == 0) {
        #pragma unroll
        for (int r = 0; r < 4; ++r) {
            sm[w][quad * 4 + r] = mrow[r];
            sl[w][quad * 4 + r] = lrow[r];
        }
    }
    __syncthreads();
    float wgt[4], L4[4];
    #pragma unroll
    for (int r = 0; r < 4; ++r) {
        int qrow = quad * 4 + r;
        float mm = -INFINITY;
        #pragma unroll
        for (int gg = 0; gg < 4; ++gg) mm = fmaxf(mm, sm[qsub * 4 + gg][qrow]);
        float LL = 0.f;
        #pragma unroll
        for (int gg = 0; gg < 4; ++gg)
            LL += exp2f(sm[qsub * 4 + gg][qrow] - mm) * sl[qsub * 4 + gg][qrow];
        wgt[r] = exp2f(mrow[r] - mm);
        L4[r] = LL;
    }
    if (g == 0 && l15 == 0) {
        #pragma unroll
        for (int r = 0; r < 4; ++r) sLf[qsub * 16 + quad * 4 + r] = L4[r];
    }

    float* obuf = (float*)skf;
    for (int gg = 0; gg < 4; ++gg) {
        if (g == gg) {
            #pragma unroll
            for (int r = 0; r < 4; ++r) {
                int idx = (qsub * 16 + quad * 4 + r) * 33 + l15;
                float v0 = wgt[r] * acc0[r];
                float v1 = wgt[r] * acc1[r];
                if (gg == 0) { obuf[idx] = v0; obuf[idx + 16] = v1; }
                else         { obuf[idx] += v0; obuf[idx + 16] += v1; }
            }
        }
        __syncthreads();
    }

    for (int i = tid; i < 1024; i += 512) {
        int ql = i >> 5, d = i & 31;
        int qq = q0 + ql;
        if (qq < NQ_)
            xout[(size_t)(b * NQ_ + qq) * 256 + h * 32 + d] = obuf[ql * 33 + d] / sLf[ql];
    }

    // ----------------- fused outproj epilogue (fan-in) -----------------
    __threadfence();                 // release this block's xout stores
    __syncthreads();                 // all threads have fenced
    if (tid == 0)
        sArrive = atomicAdd(&cnt[b * 29 + qb], 1u);
    __syncthreads();
    if (sArrive != 7u) return;       // not the last head for this q-tile
    __threadfence();                 // acquire: other heads' xout now visible

    // outproj for rows q0..q0+31 (all 256 cols), K=256.
    // wave w: row-half rh = w&1 (16 rows), col-group cg = w>>1 (64 cols).
    {
        const int rh = w & 1, cg = w >> 1;
        const int qq = q0 + rh * 16 + l15;
        const bool avalid = qq < NQ_;
        const float* xr = xout + (size_t)(b * NQ_ + qq) * 256;

        f16x8 ah[8], al[8];
        #pragma unroll
        for (int kc = 0; kc < 8; ++kc) {
            float4 a0 = make_float4(0.f, 0.f, 0.f, 0.f), a1 = a0;
            if (avalid) {
                a0 = *(const float4*)(xr + kc * 32 + quad * 8);
                a1 = *(const float4*)(xr + kc * 32 + quad * 8 + 4);
            }
            float av[8] = {a0.x, a0.y, a0.z, a0.w, a1.x, a1.y, a1.z, a1.w};
            #pragma unroll
            for (int j = 0; j < 8; ++j) {
                _Float16 hh = (_Float16)av[j];
                ah[kc][j] = hh;
                al[kc][j] = (_Float16)(av[j] - (float)hh);
            }
        }

        f32x4 acc[4] = {{0.f,0.f,0.f,0.f},{0.f,0.f,0.f,0.f},{0.f,0.f,0.f,0.f},{0.f,0.f,0.f,0.f}};
        #pragma unroll
        for (int kc = 0; kc < 8; ++kc) {
            #pragma unroll
            for (int nt = 0; nt < 4; ++nt) {
                size_t gb = (size_t)(cg * 64 + nt * 16 + l15) * 256 + kc * 32 + quad * 8;
                f16x8 bh = *(const f16x8*)(wph + gb);
                f16x8 bl = *(const f16x8*)(wpl + gb);
                acc[nt] = __builtin_amdgcn_mfma_f32_16x16x32_f16(ah[kc], bh, acc[nt], 0, 0, 0);
                acc[nt] = __builtin_amdgcn_mfma_f32_16x16x32_f16(ah[kc], bl, acc[nt], 0, 0, 0);
                acc[nt] = __builtin_amdgcn_mfma_f32_16x16x32_f16(al[kc], bh, acc[nt], 0, 0, 0);
            }
        }

        #pragma unroll
        for (int nt = 0; nt < 4; ++nt) {
            int n = cg * 64 + nt * 16 + l15;
            float bs = bp[n];
            #pragma unroll
            for (int r = 0; r < 4; ++r) {
                int qrow = q0 + rh * 16 + quad * 4 + r;
                if (qrow < NQ_)
                    out[(size_t)(b * NQ_ + qrow) * 256 + n] = acc[nt][r] + bs;
            }
        }
    }
}

// ---------------------------------------------------------------------------
extern "C" void kernel_launch(void* const* d_in, const int* in_sizes, int n_in,
                              void* d_out, int out_size, void* d_ws, size_t ws_size,
                              hipStream_t stream)
{
    const float* query = (const float*)d_in[1];
    const float* ref2d = (const float*)d_in[2];
    const float* kin   = (const float*)d_in[3];
    const float* vin   = (const float*)d_in[4];
    const unsigned char* mask = (const unsigned char*)d_in[6];
    const float* W1x = (const float*)d_in[7];
    const float* b1x = (const float*)d_in[8];
    const float* W2x = (const float*)d_in[9];
    const float* W1y = (const float*)d_in[10];
    const float* b1y = (const float*)d_in[11];
    const float* W2y = (const float*)d_in[12];
    const float* Wq  = (const float*)d_in[13];
    const float* bq  = (const float*)d_in[14];
    const float* Wk  = (const float*)d_in[15];
    const float* bk  = (const float*)d_in[16];
    const float* Wv  = (const float*)d_in[17];
    const float* bv  = (const float*)d_in[18];
    const float* Wp  = (const float*)d_in[19];
    const float* bp  = (const float*)d_in[20];

    // Workspace ~18.9 MB (proven-safe footprint 27.8 MB)
    char* wsb = (char*)d_ws;
    unsigned short* qbf = (unsigned short*)(wsb);               //   983040 B
    unsigned short* kbf = (unsigned short*)(wsb +   983040);    //  4194304 B
    unsigned short* vbf = (unsigned short*)(wsb +  5177344);    //  4194304 B
    float* rxws = (float*)(wsb +  9371648);                     //  3686400 B
    float* ryws = (float*)(wsb + 13058048);                     //  3686400 B
    float* xws  = (float*)(wsb + 16744448);                     //  1843200 B
    unsigned short* wph = (unsigned short*)(wsb + 18587648);    //   131072 B
    unsigned short* wpl = (unsigned short*)(wsb + 18718720);    //   131072 B
    unsigned int* cnt   = (unsigned int*)(wsb + 18849792);      //      232 B
    float* out  = (float*)d_out;

    const float qscale = LOG2E / sqrtf(32.0f);   // exp2-domain softmax

    stage1_kernel<<<751, 256, 0, stream>>>(
        query, kin, vin, Wq, Wk, Wv, Wp, bq, bk, bv, qbf, kbf, vbf, qscale,
        ref2d, W1x, b1x, W1y, b1y, W2x, W2y, rxws, ryws, wph, wpl, cnt);
    attn_mfma_kernel<<<dim3(29, 8, B_), 512, 0, stream>>>(
        qbf, kbf, vbf, rxws, ryws, mask, xws, wph, wpl, bp, out, cnt);
}

// Round 14
// 198.824 us; speedup vs baseline: 1.5960x; 1.5960x over previous
//
#include <hip/hip_runtime.h>
#include <hip/hip_bf16.h>
#include <cmath>

// Problem constants
#define B_ 2
#define NQ_ 900
#define N_ 4096
#define LOG2E 1.4426950408889634f

typedef __attribute__((ext_vector_type(4))) float f32x4;
typedef __attribute__((ext_vector_type(8))) short s16x8;
typedef __attribute__((ext_vector_type(8))) _Float16 f16x8;

__device__ inline short f2bf(float x) {
    union { __hip_bfloat16 b; short s; } u;
    u.b = __float2bfloat16(x);
    return u.s;
}
__device__ inline short f2h(float x) {
    _Float16 h = (_Float16)x;
    return __builtin_bit_cast(short, h);
}

// DPP rotate within 16-lane row (VALU pipe; replaces ds_bpermute shuffles)
template <int CTRL>
__device__ inline float dppf(float x) {
    int xi = __builtin_bit_cast(int, x);
    int r = __builtin_amdgcn_update_dpp(xi, xi, CTRL, 0xF, 0xF, true);
    return __builtin_bit_cast(float, r);
}
__device__ inline float rowmax16(float v) {
    v = fmaxf(v, dppf<0x121>(v));
    v = fmaxf(v, dppf<0x122>(v));
    v = fmaxf(v, dppf<0x124>(v));
    v = fmaxf(v, dppf<0x128>(v));
    return v;
}
__device__ inline float rowsum16(float v) {
    v += dppf<0x121>(v);
    v += dppf<0x122>(v);
    v += dppf<0x124>(v);
    v += dppf<0x128>(v);
    return v;
}

// ---------------------------------------------------------------------------
// Stage 1 v3 (FUSED proj + rpe3 + Wp-prep).
//  blocks 0..284  : proj, A-fragments in registers, Bb full-K 32 KB LDS
//  blocks 285..734: rpe3, 4 queries/block
//  blocks 735..750: Wp -> transposed f16 hi/lo pairs (no extra launch).
// Round-13 lesson: do NOT fuse outproj into attn via fan-in atomics — the
// epilogue's live state + threadfence perturbed the attn main loop 4x.
// Side-by-side block fusion (this kernel) is the safe pattern.
// ---------------------------------------------------------------------------
__global__ __launch_bounds__(256) void stage1_kernel(
    const float* __restrict__ query, const float* __restrict__ kin,
    const float* __restrict__ vin,
    const float* __restrict__ Wq, const float* __restrict__ Wk,
    const float* __restrict__ Wv, const float* __restrict__ Wp,
    const float* __restrict__ bqv, const float* __restrict__ bkv,
    const float* __restrict__ bvv,
    unsigned short* __restrict__ qbf, unsigned short* __restrict__ kbf,
    unsigned short* __restrict__ vbf, float qscale,
    const float* __restrict__ ref2d,
    const float* __restrict__ W1x, const float* __restrict__ b1x,
    const float* __restrict__ W1y, const float* __restrict__ b1y,
    const float* __restrict__ W2x, const float* __restrict__ W2y,
    float* __restrict__ rpe_x, float* __restrict__ rpe_y,
    unsigned short* __restrict__ wph, unsigned short* __restrict__ wpl)
{
    __shared__ uint4 smem[2560];          // 40 KB union
    const int bx = blockIdx.x;
    const int tid = threadIdx.x;
    const int w = tid >> 6, l = tid & 63, quad = l >> 4, l15 = l & 15;

    if (bx < 285) {
        // ------------------------------ proj ------------------------------
        short* Bb = (short*)smem;                    // 32 KB (full K, one n-tile)
        const int mtx = bx < 29 ? 0 : (bx < 157 ? 1 : 2);
        const int tile = bx - (mtx == 0 ? 0 : mtx == 1 ? 29 : 157);
        const int m0 = tile * 64;
        const float* X = mtx == 0 ? query : mtx == 1 ? kin : vin;
        const float* W = mtx == 0 ? Wq : mtx == 1 ? Wk : Wv;
        const float* bias = mtx == 0 ? bqv : mtx == 1 ? bkv : bvv;
        unsigned short* Y = mtx == 0 ? qbf : mtx == 1 ? kbf : vbf;
        const int M = mtx == 0 ? 1800 : 8192;
        const float alpha = mtx == 0 ? qscale : 1.0f;
        const int rows_per_b = mtx == 0 ? 900 : 4096;
        const int ROWS = mtx == 0 ? 960 : 4096;
        const int wq = tid & 3, mm = tid >> 2;

        // A-fragments in registers: row = m0 + w*16 + l15, k = kc*32+quad*8+j
        s16x8 afr[8];
        {
            const int arow = m0 + w * 16 + l15;
            const bool avalid = arow < M;
            const float* xr = X + (size_t)arow * 256;
            #pragma unroll
            for (int kc = 0; kc < 8; ++kc) {
                float4 a0 = make_float4(0.f, 0.f, 0.f, 0.f), a1 = a0;
                if (avalid) {
                    a0 = *(const float4*)(xr + kc * 32 + quad * 8);
                    a1 = *(const float4*)(xr + kc * 32 + quad * 8 + 4);
                }
                unsigned pk0 = (unsigned)(unsigned short)f2bf(a0.x) | ((unsigned)(unsigned short)f2bf(a0.y) << 16);
                unsigned pk1 = (unsigned)(unsigned short)f2bf(a0.z) | ((unsigned)(unsigned short)f2bf(a0.w) << 16);
                unsigned pk2 = (unsigned)(unsigned short)f2bf(a1.x) | ((unsigned)(unsigned short)f2bf(a1.y) << 16);
                unsigned pk3 = (unsigned)(unsigned short)f2bf(a1.z) | ((unsigned)(unsigned short)f2bf(a1.w) << 16);
                uint4 pk = make_uint4(pk0, pk1, pk2, pk3);
                afr[kc] = __builtin_bit_cast(s16x8, pk);
            }
        }

        for (int nt0 = 0; nt0 < 4; ++nt0) {
            const int n0 = nt0 * 64;
            {
                const float* wcol = W + n0 + mm;
                #pragma unroll
                for (int it = 0; it < 8; ++it) {
                    int g2 = it * 4 + wq;
                    uint4 wk4;
                    wk4.x = (unsigned)(unsigned short)f2bf(wcol[(g2 * 8 + 0) * 256])
                          | ((unsigned)(unsigned short)f2bf(wcol[(g2 * 8 + 1) * 256]) << 16);
                    wk4.y = (unsigned)(unsigned short)f2bf(wcol[(g2 * 8 + 2) * 256])
                          | ((unsigned)(unsigned short)f2bf(wcol[(g2 * 8 + 3) * 256]) << 16);
                    wk4.z = (unsigned)(unsigned short)f2bf(wcol[(g2 * 8 + 4) * 256])
                          | ((unsigned)(unsigned short)f2bf(wcol[(g2 * 8 + 5) * 256]) << 16);
                    wk4.w = (unsigned)(unsigned short)f2bf(wcol[(g2 * 8 + 6) * 256])
                          | ((unsigned)(unsigned short)f2bf(wcol[(g2 * 8 + 7) * 256]) << 16);
                    *(uint4*)(Bb + (it * 256 + mm * 4 + wq) * 8) = wk4;
                }
            }
            __syncthreads();

            f32x4 acc[4] = {{0.f,0.f,0.f,0.f},{0.f,0.f,0.f,0.f},{0.f,0.f,0.f,0.f},{0.f,0.f,0.f,0.f}};
            #pragma unroll
            for (int kc = 0; kc < 8; ++kc) {
                #pragma unroll
                for (int nt = 0; nt < 4; ++nt) {
                    s16x8 bf = *(const s16x8*)(Bb + (kc * 256 + (nt * 16 + l15) * 4 + quad) * 8);
                    acc[nt] = __builtin_amdgcn_mfma_f32_16x16x32_bf16(afr[kc], bf, acc[nt], 0, 0, 0);
                }
            }

            #pragma unroll
            for (int nt = 0; nt < 4; ++nt) {
                int n = n0 + nt * 16 + l15;
                float bs = bias[n];
                int h = n >> 5, d = n & 31;
                #pragma unroll
                for (int r = 0; r < 4; ++r) {
                    int row = m0 + w * 16 + quad * 4 + r;
                    if (row < M) {
                        int b = row / rows_per_b;
                        int pos = row - b * rows_per_b;
                        Y[((size_t)(b * 8 + h) * ROWS + pos) * 32 + d] =
                            (unsigned short)f2bf((acc[nt][r] + bs) * alpha);
                    }
                }
            }
            __syncthreads();
        }
    } else if (bx < 735) {
        // ------------------------------ rpe3 ------------------------------
        short* sw2h = (short*)smem;                  // 16 KB
        short* sw2l = (short*)smem + 8192;           // 16 KB
        float4* sUV = (float4*)(smem + 2048);        // 8 KB, unpadded
        const int bq0 = (bx - 285) * 4;              // 4 queries per block

        for (int i = tid; i < 8192; i += 256) {
            int g = i >> 3, j = i & 7;
            int kcg = g >> 6, rr = g & 63, n = rr >> 2, q4 = rr & 3;
            int k = kcg * 32 + q4 * 8 + j;
            float val = ((n < 8) ? W2x[k * 8 + n] : W2y[k * 8 + (n - 8)]) * LOG2E;
            _Float16 hi = (_Float16)val;
            sw2h[i] = __builtin_bit_cast(short, hi);
            sw2l[i] = f2h(val - (float)hi);
        }

        // hoist W1 coefficients (k0 = tid, k1 = tid+256) + query-independent v
        const int k0 = tid, k1 = tid + 256;
        const float w1x0a = W1x[k0], w1x1a = W1x[512 + k0];
        const float w1y0a = W1y[k0], w1y1a = W1y[512 + k0];
        const float bxa = b1x[k0], bya = b1y[k0];
        const float vxa = -(w1x0a + w1x1a), vya = -(w1y0a + w1y1a);
        const float w1x0b = W1x[k1], w1x1b = W1x[512 + k1];
        const float w1y0b = W1y[k1], w1y1b = W1y[512 + k1];
        const float bxb = b1x[k1], byb = b1y[k1];
        const float vxb = -(w1x0b + w1x1b), vyb = -(w1y0b + w1y1b);

        const int wrow = w;
        const int row = wrow * 16 + l15;
        const float pc = (row + 0.5f) * 16.0f;

        for (int qi = 0; qi < 4; ++qi) {
            const int bq = bq0 + qi;
            {
                const float4 bb = *(const float4*)(ref2d + (size_t)bq * 4);
                float x1 = bb.x - bb.z * 0.5f, x2 = bb.x + bb.z * 0.5f;
                float y1 = bb.y - bb.w * 0.5f, y2 = bb.y + bb.w * 0.5f;
                sUV[k0] = make_float4(fmaf(w1x0a, x1, fmaf(w1x1a, x2, bxa)), vxa,
                                      fmaf(w1y0a, y1, fmaf(w1y1a, y2, bya)), vya);
                sUV[k1] = make_float4(fmaf(w1x0b, x1, fmaf(w1x1b, x2, bxb)), vxb,
                                      fmaf(w1y0b, y1, fmaf(w1y1b, y2, byb)), vyb);
            }
            __syncthreads();

            f32x4 accx = {0.f, 0.f, 0.f, 0.f}, accy = {0.f, 0.f, 0.f, 0.f};
            for (int kc = 0; kc < 16; ++kc) {
                f16x8 axh, axl, ayh, ayl;
                #pragma unroll
                for (int i = 0; i < 8; ++i) {
                    float4 u = sUV[kc * 32 + quad * 8 + i];
                    float hx = fmaxf(fmaf(u.y, pc, u.x), 0.f);
                    float hy = fmaxf(fmaf(u.w, pc, u.z), 0.f);
                    _Float16 xh = (_Float16)hx;
                    _Float16 yh = (_Float16)hy;
                    axh[i] = xh;
                    axl[i] = (_Float16)(hx - (float)xh);
                    ayh[i] = yh;
                    ayl[i] = (_Float16)(hy - (float)yh);
                }
                f16x8 bh = *(const f16x8*)(sw2h + (kc * 64 + l15 * 4 + quad) * 8);
                f16x8 bl = *(const f16x8*)(sw2l + (kc * 64 + l15 * 4 + quad) * 8);
                accx = __builtin_amdgcn_mfma_f32_16x16x32_f16(axh, bh, accx, 0, 0, 0);
                accx = __builtin_amdgcn_mfma_f32_16x16x32_f16(axh, bl, accx, 0, 0, 0);
                accx = __builtin_amdgcn_mfma_f32_16x16x32_f16(axl, bh, accx, 0, 0, 0);
                accy = __builtin_amdgcn_mfma_f32_16x16x32_f16(ayh, bh, accy, 0, 0, 0);
                accy = __builtin_amdgcn_mfma_f32_16x16x32_f16(ayh, bl, accy, 0, 0, 0);
                accy = __builtin_amdgcn_mfma_f32_16x16x32_f16(ayl, bh, accy, 0, 0, 0);
            }

            #pragma unroll
            for (int rr = 0; rr < 4; ++rr) {
                int row_out = wrow * 16 + quad * 4 + rr;
                if (l15 < 8) rpe_x[((size_t)l15 * 1800 + bq) * 64 + row_out] = accx[rr];
                else         rpe_y[((size_t)(l15 - 8) * 1800 + bq) * 64 + row_out] = accy[rr];
            }
            __syncthreads();   // before next query overwrites sUV
        }
    } else {
        // --------------------- Wp -> f16 hi/lo W^T ------------------------
        const int tile = bx - 735;                   // 0..15
        const int kt = tile >> 2, ntile = tile & 3;
        unsigned short* th = (unsigned short*)smem;  // 64*72 ushort = 9.2 KB
        unsigned short* tl = th + 64 * 72;           // 9.2 KB
        #pragma unroll
        for (int p = 0; p < 4; ++p) {
            int kl = p * 16 + (tid >> 4);
            int nl = (tid & 15) * 4;
            float4 v = *(const float4*)(Wp + (size_t)(kt * 64 + kl) * 256 + ntile * 64 + nl);
            float vv[4] = {v.x, v.y, v.z, v.w};
            #pragma unroll
            for (int i = 0; i < 4; ++i) {
                _Float16 h = (_Float16)vv[i];
                th[(nl + i) * 72 + kl] = (unsigned short)__builtin_bit_cast(short, h);
                tl[(nl + i) * 72 + kl] = (unsigned short)f2h(vv[i] - (float)h);
            }
        }
        __syncthreads();
        #pragma unroll
        for (int p = 0; p < 2; ++p) {
            int nl = p * 32 + (tid >> 3);
            int k8 = (tid & 7) * 8;
            uint4 pk;
            unsigned short* ps = (unsigned short*)&pk;
            #pragma unroll
            for (int j = 0; j < 8; ++j) ps[j] = th[nl * 72 + k8 + j];
            *(uint4*)(wph + (size_t)(ntile * 64 + nl) * 256 + kt * 64 + k8) = pk;
            #pragma unroll
            for (int j = 0; j < 8; ++j) ps[j] = tl[nl * 72 + k8 + j];
            *(uint4*)(wpl + (size_t)(ntile * 64 + nl) * 256 + kt * 64 + k8) = pk;
        }
    }
}

// ---------------------------------------------------------------------------
// Output projection v2: A-fragments (X hi/lo split) in REGISTERS (rows are
// wave-private), B-fragments direct from prep'd wph/wpl. Zero LDS, zero
// barriers — the k-loop is pure MFMA + global reads.
// ---------------------------------------------------------------------------
__global__ __launch_bounds__(256) void outproj_kernel(
    const float* __restrict__ X,
    const unsigned short* __restrict__ wph, const unsigned short* __restrict__ wpl,
    const float* __restrict__ bias, float* __restrict__ Y, int M)
{
    const int tid = threadIdx.x;
    const int m0 = blockIdx.x * 64, n0 = blockIdx.y * 64;
    const int w = tid >> 6, l = tid & 63, quad = l >> 4, l15 = l & 15;

    const int arow = m0 + w * 16 + l15;
    const bool avalid = arow < M;
    const float* xr = X + (size_t)arow * 256;

    f16x8 ah[8], al[8];
    #pragma unroll
    for (int kc = 0; kc < 8; ++kc) {
        float4 a0 = make_float4(0.f, 0.f, 0.f, 0.f), a1 = a0;
        if (avalid) {
            a0 = *(const float4*)(xr + kc * 32 + quad * 8);
            a1 = *(const float4*)(xr + kc * 32 + quad * 8 + 4);
        }
        float av[8] = {a0.x, a0.y, a0.z, a0.w, a1.x, a1.y, a1.z, a1.w};
        #pragma unroll
        for (int j = 0; j < 8; ++j) {
            _Float16 h = (_Float16)av[j];
            ah[kc][j] = h;
            al[kc][j] = (_Float16)(av[j] - (float)h);
        }
    }

    f32x4 acc[4] = {{0.f,0.f,0.f,0.f},{0.f,0.f,0.f,0.f},{0.f,0.f,0.f,0.f},{0.f,0.f,0.f,0.f}};
    #pragma unroll
    for (int kc = 0; kc < 8; ++kc) {
        #pragma unroll
        for (int nt = 0; nt < 4; ++nt) {
            size_t gb = (size_t)(n0 + nt * 16 + l15) * 256 + kc * 32 + quad * 8;
            f16x8 bh = *(const f16x8*)(wph + gb);
            f16x8 bl = *(const f16x8*)(wpl + gb);
            acc[nt] = __builtin_amdgcn_mfma_f32_16x16x32_f16(ah[kc], bh, acc[nt], 0, 0, 0);
            acc[nt] = __builtin_amdgcn_mfma_f32_16x16x32_f16(ah[kc], bl, acc[nt], 0, 0, 0);
            acc[nt] = __builtin_amdgcn_mfma_f32_16x16x32_f16(al[kc], bh, acc[nt], 0, 0, 0);
        }
    }

    #pragma unroll
    for (int nt = 0; nt < 4; ++nt) {
        int n = n0 + nt * 16 + l15;
        float bs = bias[n];
        #pragma unroll
        for (int r = 0; r < 4; ++r) {
            int row = m0 + w * 16 + quad * 4 + r;
            if (row < M)
                Y[(size_t)row * 256 + n] = acc[nt][r] + bs;
        }
    }
}

// ---------------------------------------------------------------------------
// MFMA flash attention (round-1/8 verified config — unchanged).
// ---------------------------------------------------------------------------
__global__ __launch_bounds__(512, 4) void attn_mfma_kernel(
    const unsigned short* __restrict__ qb16, const unsigned short* __restrict__ kb16,
    const unsigned short* __restrict__ vb16,
    const float* __restrict__ rpe_x, const float* __restrict__ rpe_y,
    const unsigned char* __restrict__ mask, float* __restrict__ xout)
{
    __shared__ short skf[4 * 2048];
    __shared__ short svt[4 * 2048];
    __shared__ short spb[8 * 544];
    __shared__ float ry[32 * 65];
    __shared__ unsigned long long smaskb[64];
    __shared__ float sm[8][16], sl[8][16], sLf[32];

    const int tid = threadIdx.x;
    const int qb = blockIdx.x, h = blockIdx.y, b = blockIdx.z;
    const int q0 = qb * 32;
    const int w = tid >> 6, l = tid & 63;
    const int qsub = w >> 2, g = w & 3;
    const int quad = l >> 4, l15 = l & 15;

    const unsigned short* qg = qb16 + (size_t)(b * 8 + h) * 960 * 32;
    const unsigned short* kg = kb16 + (size_t)(b * 8 + h) * 4096 * 32;
    const unsigned short* vg = vb16 + (size_t)(b * 8 + h) * 4096 * 32;
    const float* rxh = rpe_x + ((size_t)h * 1800 + b * NQ_) * 64;
    const float* ryh = rpe_y + ((size_t)h * 1800 + b * NQ_) * 64;

    for (int i = tid; i < 2048; i += 512) {
        int qq = q0 + (i >> 6), pos = i & 63;
        float vy = 0.f;
        if (qq < NQ_)
            vy = ryh[(size_t)qq * 64 + pos];
        ry[(i >> 6) * 65 + pos] = vy;
    }
    #pragma unroll
    for (int j = 0; j < 8; ++j) {
        int c = w * 8 + j;
        unsigned long long bits = __ballot(mask[(size_t)b * N_ + c * 64 + l] != 0);
        if (l == 0) smaskb[c] = bits;
    }

    s16x8 qa = *(const s16x8*)(qg + (size_t)(q0 + qsub * 16 + l15) * 32 + quad * 8);

    f32x4 rx4[4];
    #pragma unroll
    for (int t = 0; t < 4; ++t)
        #pragma unroll
        for (int r = 0; r < 4; ++r) {
            int qq = q0 + qsub * 16 + quad * 4 + r;
            rx4[t][r] = (qq < NQ_) ? rxh[(size_t)qq * 64 + t * 16 + l15] : 0.f;
        }

    const int sg = tid >> 7, role = (tid >> 6) & 1, stl = tid & 63;
    int eoff[4];
    if (role == 0) {
        #pragma unroll
        for (int t = 0; t < 4; ++t)
            eoff[t] = (t * 16 + (stl & 15)) * 32 + (stl >> 4) * 8;
    } else {
        #pragma unroll
        for (int t = 0; t < 4; ++t)
            eoff[t] = stl * 32 + t * 8;
    }
    const unsigned short* src = role ? vg : kg;

    uint4 pf[4];
    {
        size_t cb = (size_t)(sg * 16) * 2048;
        #pragma unroll
        for (int t = 0; t < 4; ++t) pf[t] = *(const uint4*)(src + cb + eoff[t]);
    }

    float mrow[4] = {-INFINITY, -INFINITY, -INFINITY, -INFINITY};
    float lrow[4] = {0.f, 0.f, 0.f, 0.f};
    f32x4 acc0 = {0.f, 0.f, 0.f, 0.f}, acc1 = {0.f, 0.f, 0.f, 0.f};
    short* pw = spb + w * 544;

    for (int i = 0; i < 16; ++i) {
        __syncthreads();
        if (role == 0) {
            #pragma unroll
            for (int t = 0; t < 4; ++t)
                *(uint4*)(skf + sg * 2048 + (t * 64 + stl) * 8) = pf[t];
        } else {
            short* vtw = svt + sg * 2048;
            #pragma unroll
            for (int t = 0; t < 4; ++t) {
                const unsigned short* pv = (const unsigned short*)&pf[t];
                #pragma unroll
                for (int j = 0; j < 8; ++j) {
                    int d = t * 8 + j;
                    vtw[d * 64 + (((stl >> 3) ^ (d & 7)) << 3) + (stl & 7)] = (short)pv[j];
                }
            }
        }
        __syncthreads();

        {
            int inext = (i + 1 < 16) ? i + 1 : 15;
            size_t cb = (size_t)(sg * 16 + inext) * 2048;
            #pragma unroll
            for (int t = 0; t < 4; ++t) pf[t] = *(const uint4*)(src + cb + eoff[t]);
        }

        const int cgc = g * 16 + i;
        const short* kf = skf + g * 2048;

        f32x4 sc[4];
        #pragma unroll
        for (int t = 0; t < 4; ++t) {
            s16x8 kb = *(const s16x8*)(kf + (t * 64 + l) * 8);
            sc[t] = __builtin_amdgcn_mfma_f32_16x16x32_bf16(qa, kb, rx4[t], 0, 0, 0);
        }
        float ryv[4];
        #pragma unroll
        for (int r = 0; r < 4; ++r)
            ryv[r] = ry[(qsub * 16 + quad * 4 + r) * 65 + cgc];
        unsigned long long mb = smaskb[cgc];
        if (mb) {
            #pragma unroll
            for (int t = 0; t < 4; ++t) {
                float mk = ((mb >> (t * 16 + l15)) & 1ULL) ? -144.2695f : 0.f;
                #pragma unroll
                for (int r = 0; r < 4; ++r) sc[t][r] += mk;
            }
        }

        float cmr[4];
        #pragma unroll
        for (int r = 0; r < 4; ++r)
            cmr[r] = fmaxf(fmaxf(sc[0][r], sc[1][r]), fmaxf(sc[2][r], sc[3][r])) + ryv[r];

        int ok = (cmr[0] <= mrow[0] + 8.f) & (cmr[1] <= mrow[1] + 8.f)
               & (cmr[2] <= mrow[2] + 8.f) & (cmr[3] <= mrow[3] + 8.f);
        if (!__all(ok)) {
            #pragma unroll
            for (int r = 0; r < 4; ++r) {
                float cm = rowmax16(cmr[r]);
                float mnew = fmaxf(mrow[r], cm);
                float al = exp2f(mrow[r] - mnew);
                mrow[r] = mnew;
                lrow[r] *= al;
                acc0[r] *= al;
                acc1[r] *= al;
            }
        }

        float msub[4];
        #pragma unroll
        for (int r = 0; r < 4; ++r) msub[r] = mrow[r] - ryv[r];
        #pragma unroll
        for (int t = 0; t < 4; ++t)
            #pragma unroll
            for (int r = 0; r < 4; ++r)
                sc[t][r] = exp2f(sc[t][r] - msub[r]);
        #pragma unroll
        for (int r = 0; r < 4; ++r)
            lrow[r] += (sc[0][r] + sc[1][r]) + (sc[2][r] + sc[3][r]);

        const short* vt = svt + g * 2048;
        #pragma unroll
        for (int hh = 0; hh < 2; ++hh) {
            #pragma unroll
            for (int tt = 0; tt < 2; ++tt) {
                int t = hh * 2 + tt;
                int gphys = (tt * 2 + (l15 >> 3)) ^ quad;
                #pragma unroll
                for (int r = 0; r < 4; ++r)
                    pw[(gphys * 17 + quad * 4 + r) * 8 + (l15 & 7)] = f2bf(sc[t][r]);
            }
            int gph_r = quad ^ (l15 >> 2);
            s16x8 pa  = *(const s16x8*)(pw + (gph_r * 17 + l15) * 8);
            int ksw = ((hh * 4 + quad) ^ (l15 & 7)) * 8;
            s16x8 vb0 = *(const s16x8*)(vt + l15 * 64 + ksw);
            s16x8 vb1 = *(const s16x8*)(vt + (16 + l15) * 64 + ksw);
            acc0 = __builtin_amdgcn_mfma_f32_16x16x32_bf16(pa, vb0, acc0, 0, 0, 0);
            acc1 = __builtin_amdgcn_mfma_f32_16x16x32_bf16(pa, vb1, acc1, 0, 0, 0);
        }
    }

    #pragma unroll
    for (int r = 0; r < 4; ++r) lrow[r] = rowsum16(lrow[r]);

    __syncthreads();
    if (l15 == 0) {
        #pragma unroll
        for (int r = 0; r < 4; ++r) {
            sm[w][quad * 4 + r] = mrow[r];
            sl[w][quad * 4 + r] = lrow[r];
        }
    }
    __syncthreads();
    float wgt[4], L4[4];
    #pragma unroll
    for (int r = 0; r < 4; ++r) {
        int qrow = quad * 4 + r;
        float mm = -INFINITY;
        #pragma unroll
        for (int gg = 0; gg < 4; ++gg) mm = fmaxf(mm, sm[qsub * 4 + gg][qrow]);
        float LL = 0.f;
        #pragma unroll
        for (int gg = 0; gg < 4; ++gg)
            LL += exp2f(sm[qsub * 4 + gg][qrow] - mm) * sl[qsub * 4 + gg][qrow];
        wgt[r] = exp2f(mrow[r] - mm);
        L4[r] = LL;
    }
    if (g == 0 && l15 == 0) {
        #pragma unroll
        for (int r = 0; r < 4; ++r) sLf[qsub * 16 + quad * 4 + r] = L4[r];
    }

    float* obuf = (float*)skf;
    for (int gg = 0; gg < 4; ++gg) {
        if (g == gg) {
            #pragma unroll
            for (int r = 0; r < 4; ++r) {
                int idx = (qsub * 16 + quad * 4 + r) * 33 + l15;
                float v0 = wgt[r] * acc0[r];
                float v1 = wgt[r] * acc1[r];
                if (gg == 0) { obuf[idx] = v0; obuf[idx + 16] = v1; }
                else         { obuf[idx] += v0; obuf[idx + 16] += v1; }
            }
        }
        __syncthreads();
    }

    for (int i = tid; i < 1024; i += 512) {
        int ql = i >> 5, d = i & 31;
        int qq = q0 + ql;
        if (qq < NQ_)
            xout[(size_t)(b * NQ_ + qq) * 256 + h * 32 + d] = obuf[ql * 33 + d] / sLf[ql];
    }
}

// ---------------------------------------------------------------------------
extern "C" void kernel_launch(void* const* d_in, const int* in_sizes, int n_in,
                              void* d_out, int out_size, void* d_ws, size_t ws_size,
                              hipStream_t stream)
{
    const float* query = (const float*)d_in[1];
    const float* ref2d = (const float*)d_in[2];
    const float* kin   = (const float*)d_in[3];
    const float* vin   = (const float*)d_in[4];
    const unsigned char* mask = (const unsigned char*)d_in[6];
    const float* W1x = (const float*)d_in[7];
    const float* b1x = (const float*)d_in[8];
    const float* W2x = (const float*)d_in[9];
    const float* W1y = (const float*)d_in[10];
    const float* b1y = (const float*)d_in[11];
    const float* W2y = (const float*)d_in[12];
    const float* Wq  = (const float*)d_in[13];
    const float* bq  = (const float*)d_in[14];
    const float* Wk  = (const float*)d_in[15];
    const float* bk  = (const float*)d_in[16];
    const float* Wv  = (const float*)d_in[17];
    const float* bv  = (const float*)d_in[18];
    const float* Wp  = (const float*)d_in[19];
    const float* bp  = (const float*)d_in[20];

    // Workspace ~18.9 MB (proven-safe footprint 27.8 MB)
    char* wsb = (char*)d_ws;
    unsigned short* qbf = (unsigned short*)(wsb);               //   983040 B
    unsigned short* kbf = (unsigned short*)(wsb +   983040);    //  4194304 B
    unsigned short* vbf = (unsigned short*)(wsb +  5177344);    //  4194304 B
    float* rxws = (float*)(wsb +  9371648);                     //  3686400 B
    float* ryws = (float*)(wsb + 13058048);                     //  3686400 B
    float* xws  = (float*)(wsb + 16744448);                     //  1843200 B
    unsigned short* wph = (unsigned short*)(wsb + 18587648);    //   131072 B
    unsigned short* wpl = (unsigned short*)(wsb + 18718720);    //   131072 B
    float* out  = (float*)d_out;

    const float qscale = LOG2E / sqrtf(32.0f);   // exp2-domain softmax

    stage1_kernel<<<751, 256, 0, stream>>>(
        query, kin, vin, Wq, Wk, Wv, Wp, bq, bk, bv, qbf, kbf, vbf, qscale,
        ref2d, W1x, b1x, W1y, b1y, W2x, W2y, rxws, ryws, wph, wpl);
    attn_mfma_kernel<<<dim3(29, 8, B_), 512, 0, stream>>>(
        qbf, kbf, vbf, rxws, ryws, mask, xws);
    outproj_kernel<<<dim3(29, 4), 256, 0, stream>>>(
        xws, wph, wpl, bp, out, 1800);
}